// Round 7
// baseline (287155.444 us; speedup 1.0000x reference)
//
#include <hip/hip_runtime.h>
#include <math.h>

#define HH 2048
#define DD 66
#define TT 4096
#define PRE 64
#define NWG 512        // 512 WGs x 256 threads; 2 WGs/CU -> 8 waves/CU
#define NTH 256
#define FSTRIDE 16     // flag padding: 16 uints = 64B per WG

// ---- numeric representation (identical to round-5, which hit the absmax floor) ----
// Weights: fp16(64*w) hi in VGPRs + int8 residual q = rint((64w - hi)*127*2^11)
// (fits +-127 exactly for |64w|<=1.42). Subnormal hi flushed at ENCODE so a
// flushing fdot2 consumer agrees with the residual.
// h: flush-aware fp16 hi + fp16((h-hi)*2048) lo.
// gate = accf/64 + accc*2^-17/... : accf*S_HI + accc*S_LO + accr*S_RS (fp32 fmaf)
#define S_HI 0.015625f
#define S_LO 7.62939453125e-06f
#define S_RS (1.0f / 16646144.0f)
#define RQ   260096.0f            // 127 * 2^11
#define F16_MIN_NORM 6.104e-05f

typedef _Float16 f16x2 __attribute__((ext_vector_type(2)));

#if defined(__HIP_DEVICE_COMPILE__) && __has_builtin(__builtin_amdgcn_fdot2)
#define FDOT2(a, b, c) __builtin_amdgcn_fdot2((a), (b), (c), false)
#else
#define FDOT2(a, b, c) fmaf((float)(a).y, (float)(b).y, fmaf((float)(a).x, (float)(b).x, (c)))
#endif

__device__ __forceinline__ f16x2 u2h(unsigned u) { return __builtin_bit_cast(f16x2, u); }

__device__ __forceinline__ unsigned long long ld8(const unsigned* p) {
  return __hip_atomic_load((const unsigned long long*)p, __ATOMIC_RELAXED,
                           __HIP_MEMORY_SCOPE_AGENT);
}

__device__ __forceinline__ int q8(float x) {
  float s = x * RQ;
  s = fminf(fmaxf(s, -127.0f), 127.0f);
  return (int)rintf(s);
}

// split one float2 of raw weights -> fp16 hi pair (flush-aware) + 2 residual bytes
__device__ __forceinline__ unsigned splitw(float2 f, f16x2* hi) {
  float a = f.x * 64.0f, b = f.y * 64.0f;
  _Float16 ha = (_Float16)a, hb = (_Float16)b;
  float fa = (float)ha, fb = (float)hb;
  if (fabsf(fa) < F16_MIN_NORM) { ha = (_Float16)0.0f; fa = 0.0f; }
  if (fabsf(fb) < F16_MIN_NORM) { hb = (_Float16)0.0f; fb = 0.0f; }
  f16x2 h; h.x = ha; h.y = hb; *hi = h;
  int qa = q8(a - fa), qb = q8(b - fb);
  return (unsigned)(qa & 255) | ((unsigned)(qb & 255) << 8);
}

// publish one h value (row rw): u16 hi at [4p+half], u16 lo at [4p+2+half]
__device__ __forceinline__ void publish16(unsigned* hpx, int slot, int p, int half, float h) {
  _Float16 a = (_Float16)h; float fa = (float)a;
  if (fabsf(fa) < F16_MIN_NORM) { a = (_Float16)0.0f; fa = 0.0f; }
  _Float16 b = (_Float16)((h - fa) * 2048.0f);
  unsigned short* u16p = (unsigned short*)hpx;
  u16p[slot * 4096 + 4 * p + half]     = __builtin_bit_cast(unsigned short, a);
  u16p[slot * 4096 + 4 * p + 2 + half] = __builtin_bit_cast(unsigned short, b);
}

__device__ __forceinline__ float sigm(float x) { return 1.0f / (1.0f + expf(-x)); }

// Spin barrier with watchdog + s_sleep backoff. Each of 256 threads polls 2 of
// the 512 WG flags. After ~2^19 polls arm abort; all waits check abort every
// 256 polls, so a deadlock TERMINATES (numeric fail w/ counters) quickly.
__device__ __forceinline__ void gbar_wait(unsigned* flags, unsigned* abortw,
                                          int target, int tid) {
  int v0 = (int)__hip_atomic_load(&flags[tid * FSTRIDE], __ATOMIC_RELAXED, __HIP_MEMORY_SCOPE_AGENT);
  int v1 = (int)__hip_atomic_load(&flags[(tid + 256) * FSTRIDE], __ATOMIC_RELAXED, __HIP_MEMORY_SCOPE_AGENT);
  int ab = 0, n = 0;
  while (!__syncthreads_and((int)(((v0 >= target) & (v1 >= target)) | ab))) {
    __builtin_amdgcn_s_sleep(2);
    v0 = (int)__hip_atomic_load(&flags[tid * FSTRIDE], __ATOMIC_RELAXED, __HIP_MEMORY_SCOPE_AGENT);
    v1 = (int)__hip_atomic_load(&flags[(tid + 256) * FSTRIDE], __ATOMIC_RELAXED, __HIP_MEMORY_SCOPE_AGENT);
    if ((++n & 255) == 0) {
      if (n >= (1 << 19))
        __hip_atomic_store(abortw, 1u, __ATOMIC_RELAXED, __HIP_MEMORY_SCOPE_AGENT);
      ab = (__hip_atomic_load(abortw, __ATOMIC_RELAXED, __HIP_MEMORY_SCOPE_AGENT) == 1u);
    }
  }
}

// one matrix pass over 2048 h-values; 4 gate-rows (one h-row) per wave.
// RES yields the packed int8 residual u32 for (g,k).
#define PASS(HB, WREG, RES)                                                    \
  _Pragma("unroll")                                                            \
  for (int k = 0; k < 8; ++k) {                                                \
    unsigned long long v0_ = ld8((HB) + 2 * (lane + 128 * k));                 \
    unsigned long long v1_ = ld8((HB) + 2 * (lane + 128 * k + 64));            \
    unsigned hh0_ = (unsigned)v0_, hl0_ = (unsigned)(v0_ >> 32);               \
    unsigned hh1_ = (unsigned)v1_, hl1_ = (unsigned)(v1_ >> 32);               \
    _Pragma("unroll")                                                          \
    for (int g = 0; g < 4; ++g) {                                              \
      accf[g] = FDOT2(WREG[g][2 * k],     u2h(hh0_), accf[g]);                 \
      accc[g] = FDOT2(WREG[g][2 * k],     u2h(hl0_), accc[g]);                 \
      accf[g] = FDOT2(WREG[g][2 * k + 1], u2h(hh1_), accf[g]);                 \
      accc[g] = FDOT2(WREG[g][2 * k + 1], u2h(hl1_), accc[g]);                 \
      unsigned u_ = (RES);                                                     \
      unsigned t0_ = ((u_ & 0xFFu) | ((u_ << 8) & 0xFF0000u)) ^ 0x64806480u;   \
      unsigned t1_ = (((u_ >> 16) & 0xFFu) | ((u_ >> 8) & 0xFF0000u)) ^ 0x64806480u; \
      accr[g] = FDOT2(u2h(t0_) - K1152, u2h(hh0_), accr[g]);                   \
      accr[g] = FDOT2(u2h(t1_) - K1152, u2h(hh1_), accr[g]);                   \
    }                                                                          \
  }

// prologue: one matrix -> fp16 hi regs + packed int8 residual via STORE (uses pkv)
#define LOADW(WPTR, WREG, STORE)                                               \
  _Pragma("unroll")                                                            \
  for (int g = 0; g < 4; ++g) {                                                \
    const float2* src_ = (const float2*)((WPTR) + (size_t)(g * HH + rw) * HH); \
    _Pragma("unroll")                                                          \
    for (int k = 0; k < 8; ++k) {                                              \
      float2 f0_ = src_[lane + 128 * k];                                       \
      float2 f1_ = src_[lane + 128 * k + 64];                                  \
      unsigned b01_ = splitw(f0_, &WREG[g][2 * k]);                            \
      unsigned b23_ = splitw(f1_, &WREG[g][2 * k + 1]);                        \
      unsigned pkv = b01_ | (b23_ << 16);                                      \
      STORE;                                                                   \
    }                                                                          \
  }

#define OUTBLK(SLOT, TOUT)                                                     \
  if (wg < DD) {                                                               \
    const float2* wrow_ = (const float2*)(Wlin + (size_t)wg * HH);             \
    float p_ = 0.0f;                                                           \
    _Pragma("unroll")                                                          \
    for (int i = 0; i < 4; ++i) {                                              \
      int P_ = tid + NTH * i;                                                  \
      unsigned long long v_ = ld8(h2px + (SLOT) * 2048 + 2 * P_);              \
      f16x2 hh_ = u2h((unsigned)v_), hl_ = u2h((unsigned)(v_ >> 32));          \
      float2 wv_ = wrow_[P_];                                                  \
      p_ = fmaf(wv_.x, fmaf((float)hl_.x, 4.8828125e-4f, (float)hh_.x), p_);   \
      p_ = fmaf(wv_.y, fmaf((float)hl_.y, 4.8828125e-4f, (float)hh_.y), p_);   \
    }                                                                          \
    _Pragma("unroll")                                                          \
    for (int sh = 32; sh > 0; sh >>= 1) p_ += __shfl_xor(p_, sh, 64);          \
    if (lane == 0) {                                                           \
      if (wave == 0) p_ += blin[wg];                                           \
      atomicAdd(&out[(size_t)(TOUT) * DD + wg], p_);                           \
    }                                                                          \
  }

__global__ __launch_bounds__(NTH, 2) void lstm_v7(
    const float* __restrict__ y,
    const float* __restrict__ Wih1, const float* __restrict__ Whh1,
    const float* __restrict__ bih1, const float* __restrict__ bhh1,
    const float* __restrict__ Wih2, const float* __restrict__ Whh2,
    const float* __restrict__ bih2, const float* __restrict__ bhh2,
    const float* __restrict__ Wlin, const float* __restrict__ blin,
    float* __restrict__ out,
    unsigned* h1px, unsigned* h2px,
    unsigned* flags1, unsigned* flags2, unsigned* abortw)
{
  // 65,664 B static LDS per block -> two blocks/CU fit in 160 KiB.
  __shared__ unsigned lds1[16 * 8 * 64];   // 32 KB Whh1 int8 residual [s][k][lane]
  __shared__ unsigned ldsb[16 * 8 * 64];   // 32 KB Whh2 int8 residual
  __shared__ float ldsB1[16], ldsB2[16];   // combined biases, s = wave*4+g

  const int tid = threadIdx.x;
  const int wg = blockIdx.x;
  const int wave = tid >> 6;               // 0..3
  const int lane = tid & 63;
  const int rowbase = wg * 4;              // 4 h-rows per WG
  const int rw = rowbase + wave;           // this wave's h-row

  f16x2 K1152; K1152.x = (_Float16)1152.0f; K1152.y = (_Float16)1152.0f;

  if (tid < 16) {
    int g = tid & 3, w = tid >> 2;
    int gro = g * HH + rowbase + w;
    ldsB1[tid] = bih1[gro] + bhh1[gro];
    ldsB2[tid] = bih2[gro] + bhh2[gro];
  }

  // persistent weights: 192 VGPRs hi + 32 VGPRs Wih2 residual; Whh residuals in LDS
  f16x2 w1[4][16], wa[4][16], wb[4][16];
  unsigned wlo2[4][8];
  LOADW(Whh1, w1, (lds1[((wave * 4 + g) * 8 + k) * 64 + lane] = pkv))
  LOADW(Wih2, wa, (wlo2[g][k] = pkv))
  LOADW(Whh2, wb, (ldsb[((wave * 4 + g) * 8 + k) * 64 + lane] = pkv))

  float c1 = 0.0f, c2 = 0.0f;   // lane-0 cell state for row rw
  __syncthreads();

  #pragma unroll 1
  for (int t = 0; t < TT; ++t) {
    const int cur = t & 1, prv = cur ^ 1;

    //================ phase 1: layer-1 gates ================
    float xa = y[(size_t)t * DD + lane];
    float xb = (lane < DD - 64) ? y[(size_t)t * DD + 64 + lane] : 0.0f;
    float accf[4], accc[4], accr[4];
    #pragma unroll
    for (int g = 0; g < 4; ++g) { accf[g] = 0.f; accc[g] = 0.f; accr[g] = 0.f; }

    if (t > 0) {  // h1_{t-1}; visibility via t-1's flags1 wait + acquire fence
      PASS((h1px + prv * 2048), w1, lds1[((wave * 4 + g) * 8 + k) * 64 + lane])
    }

    float gv[4];
    #pragma unroll
    for (int g = 0; g < 4; ++g) {
      const size_t gro = (size_t)(g * HH + rw);
      float a = fmaf(accr[g], S_RS, fmaf(accc[g], S_LO, accf[g] * S_HI));
      a = fmaf(Wih1[gro * DD + lane], xa, a);
      if (lane < DD - 64) a = fmaf(Wih1[gro * DD + 64 + lane], xb, a);
      #pragma unroll
      for (int sh = 32; sh > 0; sh >>= 1) a += __shfl_xor(a, sh, 64);
      gv[g] = a;
    }

    if (lane == 0) {
      float gi = sigm(gv[0] + ldsB1[wave * 4 + 0]);
      float gf = sigm(gv[1] + ldsB1[wave * 4 + 1]);
      float gg = tanhf(gv[2] + ldsB1[wave * 4 + 2]);
      float go = sigm(gv[3] + ldsB1[wave * 4 + 3]);
      c1 = fmaf(gf, c1, gi * gg);
      float h = go * tanhf(c1);
      publish16(h1px, cur, wg * 2 + (wave >> 1), wave & 1, h);
    }
    __syncthreads();  // drains all waves' publishes before the release flag
    if (tid == 0)
      __hip_atomic_store(&flags1[wg * FSTRIDE], (unsigned)(t + 1),
                         __ATOMIC_RELEASE, __HIP_MEMORY_SCOPE_AGENT);

    //================ phase 2: layer-2 gates ================
    #pragma unroll
    for (int g = 0; g < 4; ++g) { accf[g] = 0.f; accc[g] = 0.f; accr[g] = 0.f; }

    if (t > 0) {
      // deferred end-of-step barrier from t-1 (h2_{t-1} visibility + slot reuse)
      gbar_wait(flags2, abortw, t, tid);
      __builtin_amdgcn_fence(__ATOMIC_ACQUIRE, "agent");
      PASS((h2px + prv * 2048), wb, ldsb[((wave * 4 + g) * 8 + k) * 64 + lane])
    }

    gbar_wait(flags1, abortw, t + 1, tid);  // h1_t from all WGs
    __builtin_amdgcn_fence(__ATOMIC_ACQUIRE, "agent");
    PASS((h1px + cur * 2048), wa, wlo2[g][k])

    #pragma unroll
    for (int g = 0; g < 4; ++g) {
      float a = fmaf(accr[g], S_RS, fmaf(accc[g], S_LO, accf[g] * S_HI));
      #pragma unroll
      for (int sh = 32; sh > 0; sh >>= 1) a += __shfl_xor(a, sh, 64);
      gv[g] = a;
    }

    if (lane == 0) {
      float gi = sigm(gv[0] + ldsB2[wave * 4 + 0]);
      float gf = sigm(gv[1] + ldsB2[wave * 4 + 1]);
      float gg = tanhf(gv[2] + ldsB2[wave * 4 + 2]);
      float go = sigm(gv[3] + ldsB2[wave * 4 + 3]);
      c2 = fmaf(gf, c2, gi * gg);
      float h = go * tanhf(c2);
      publish16(h2px, cur, wg * 2 + (wave >> 1), wave & 1, h);
    }
    __syncthreads();
    if (tid == 0)
      __hip_atomic_store(&flags2[wg * FSTRIDE], (unsigned)(t + 1),
                         __ATOMIC_RELEASE, __HIP_MEMORY_SCOPE_AGENT);

    // out_{t-1} = Wlin . h2_{t-1} + blin, overlapping the deferred barrier.
    // Slot prv safe: its next writer (phase2 of t+1) is gated by flags1(t+2),
    // whose release (program-order after these loads) drains them.
    if (t >= PRE + 1) { OUTBLK(prv, t - 1 - PRE) }
  }

  //================ epilogue: out for t = TT-1 ================
  gbar_wait(flags2, abortw, TT, tid);
  __builtin_amdgcn_fence(__ATOMIC_ACQUIRE, "agent");
  { OUTBLK(((TT - 1) & 1), TT - 1 - PRE) }
}

extern "C" void kernel_launch(void* const* d_in, const int* in_sizes, int n_in,
                              void* d_out, int out_size, void* d_ws, size_t ws_size,
                              hipStream_t stream) {
  const float* y    = (const float*)d_in[0];
  const float* Wih1 = (const float*)d_in[1];
  const float* Whh1 = (const float*)d_in[2];
  const float* bih1 = (const float*)d_in[3];
  const float* bhh1 = (const float*)d_in[4];
  const float* Wih2 = (const float*)d_in[5];
  const float* Whh2 = (const float*)d_in[6];
  const float* bih2 = (const float*)d_in[7];
  const float* bhh2 = (const float*)d_in[8];
  const float* Wlin = (const float*)d_in[9];
  const float* blin = (const float*)d_in[10];
  // d_in[11] = pre_output_len (64), compiled in as PRE.
  float* out = (float*)d_out;

  unsigned* ws = (unsigned*)d_ws;
  unsigned* h1px   = ws;                      // 4096 u32 (2 slots x 1024 pairs x hi/lo)
  unsigned* h2px   = h1px + 4096;             // 4096 u32
  unsigned* flags1 = h2px + 4096;             // 8192 u32 (512 WGs x 16)
  unsigned* flags2 = flags1 + NWG * FSTRIDE;  // 8192 u32
  unsigned* abortw = flags2 + NWG * FSTRIDE;  // 1 u32

  void* args[] = { &y, &Wih1, &Whh1, &bih1, &bhh1, &Wih2, &Whh2, &bih2, &bhh2,
                   &Wlin, &blin, &out, &h1px, &h2px, &flags1, &flags2, &abortw };
  hipError_t e = hipLaunchCooperativeKernel((const void*)lstm_v7, dim3(NWG),
                                            dim3(NTH), args, 0, stream);
  if (e != hipSuccess) {
    // Fallback: regular launch. At 2 blocks/CU, 512 blocks on 256 CUs are all
    // co-resident in practice; if not, the watchdog aborts and the kernel
    // terminates (clean numeric failure) rather than hanging the container.
    hipLaunchKernelGGL(lstm_v7, dim3(NWG), dim3(NTH), 0, stream,
                       y, Wih1, Whh1, bih1, bhh1, Wih2, Whh2, bih2, bhh2,
                       Wlin, blin, out, h1px, h2px, flags1, flags2, abortw);
  }
}